// Round 6
// baseline (486.401 us; speedup 1.0000x reference)
//
#include <hip/hip_runtime.h>

#define N_ROWS 100000
#define IN_F   8192
#define OUT_F  128
#define NNZ    2000000

#define NREG   8                                    // regions = XCDs (blockIdx & 7)
#define FLATN  (NREG * N_ROWS)                      // 800000 (region-major counters)
#define SCAN_B 1024
#define NBLK2  ((FLATN + SCAN_B - 1) / SCAN_B)      // 782
#define NPAD2  (NBLK2 * SCAN_B)                     // 800768

// ---------------------------------------------------------------------------
// transpose weight [OUT_F, IN_F] -> wT [IN_F, OUT_F]
// ---------------------------------------------------------------------------
__global__ void transpose_w(const float* __restrict__ w, float* __restrict__ wT) {
    __shared__ float tile[32][33];
    int x = blockIdx.x * 32 + threadIdx.x;
    int y = blockIdx.y * 32 + threadIdx.y;
    #pragma unroll
    for (int i = 0; i < 32; i += 8)
        tile[threadIdx.y + i][threadIdx.x] = w[(size_t)(y + i) * IN_F + x];
    __syncthreads();
    int tx = blockIdx.y * 32 + threadIdx.x;
    int ty = blockIdx.x * 32 + threadIdx.y;
    #pragma unroll
    for (int i = 0; i < 32; i += 8)
        wT[(size_t)(ty + i) * OUT_F + tx] = tile[threadIdx.x][threadIdx.y + i];
}

// ---------------------------------------------------------------------------
// histogram into region-major counters: region j = blockIdx & 7 (== XCD under
// default round-robin dispatch) -> counter lines are XCD-local.
// ---------------------------------------------------------------------------
__global__ void hist8(const int* __restrict__ rows, int* __restrict__ counts) {
    int i = blockIdx.x * blockDim.x + threadIdx.x;
    if (i >= NNZ) return;
    int j = blockIdx.x & 7;
    atomicAdd(&counts[j * N_ROWS + rows[i]], 1);
}

// ---------------------------------------------------------------------------
// per-block exclusive scan, IN PLACE on counts; emits block totals
// ---------------------------------------------------------------------------
__global__ void scan_blocks(int* __restrict__ counts, int* __restrict__ blockSums) {
    __shared__ int sh[SCAN_B];
    int tid = threadIdx.x;
    int gid = blockIdx.x * SCAN_B + tid;
    int v = counts[gid];
    sh[tid] = v;
    __syncthreads();
    for (int off = 1; off < SCAN_B; off <<= 1) {
        int t = (tid >= off) ? sh[tid - off] : 0;
        __syncthreads();
        sh[tid] += t;
        __syncthreads();
    }
    counts[gid] = sh[tid] - v;                     // exclusive within block
    if (tid == SCAN_B - 1) blockSums[blockIdx.x] = sh[tid];
}

// ---------------------------------------------------------------------------
// single-block exclusive scan of blockSums (NBLK2 <= SCAN_B, padding zeroed)
// ---------------------------------------------------------------------------
__global__ void scan_sums(int* __restrict__ blockSums) {
    __shared__ int sh[SCAN_B];
    int tid = threadIdx.x;
    int v = blockSums[tid];
    sh[tid] = v;
    __syncthreads();
    for (int off = 1; off < SCAN_B; off <<= 1) {
        int t = (tid >= off) ? sh[tid - off] : 0;
        __syncthreads();
        sh[tid] += t;
        __syncthreads();
    }
    blockSums[tid] = sh[tid] - v;
}

// ---------------------------------------------------------------------------
// offsets[gid] = scan value (for reduce); counts[gid] := same (cursors)
// ---------------------------------------------------------------------------
__global__ void finalize_offsets(int* __restrict__ counts, const int* __restrict__ blockSums,
                                 int* __restrict__ offsets) {
    int gid = blockIdx.x * SCAN_B + threadIdx.x;
    int off = counts[gid] + blockSums[gid >> 10];
    offsets[gid] = off;
    counts[gid] = off;                             // reuse as cursors
}

// ---------------------------------------------------------------------------
// scatter (col,val) into row-sorted order within this block's region.
// Region pairs-span + cursor lines touched by ONE XCD only (proven r5).
// ---------------------------------------------------------------------------
__global__ void scatter8(const int* __restrict__ rows, const int* __restrict__ cols,
                         const float* __restrict__ vals, int* __restrict__ cursors,
                         int2* __restrict__ pairs) {
    int i = blockIdx.x * blockDim.x + threadIdx.x;
    if (i >= NNZ) return;
    int j = blockIdx.x & 7;                        // MUST match hist8 (same grid shape)
    int r = rows[i];
    int p = atomicAdd(&cursors[j * N_ROWS + r], 1);
    pairs[p] = make_int2(cols[i], __float_as_int(vals[i]));
}

// ---------------------------------------------------------------------------
// one BLOCK per row, 4 waves x 2 region-segments each (~5 records/wave:
// 4x shorter dependent-gather chain than 1-wave/row). Nontemporal pair loads
// keep wT resident in L2. LDS combine + single coalesced store.
// ---------------------------------------------------------------------------
__global__ void __launch_bounds__(256) reduce_rows(const int2* __restrict__ pairs,
                                                   const float* __restrict__ wT,
                                                   const int* __restrict__ offsets,
                                                   const float* __restrict__ bias,
                                                   float* __restrict__ out) {
    __shared__ float2 part[3][64];
    int row  = blockIdx.x;
    int w    = threadIdx.x >> 6;
    int lane = threadIdx.x & 63;

    float2 acc = make_float2(0.f, 0.f);
    #pragma unroll
    for (int jj = 0; jj < 2; ++jj) {
        int f = (w * 2 + jj) * N_ROWS + row;
        int p = offsets[f];
        int e = offsets[f + 1];                    // contiguous region-major scan
        for (; p + 2 <= e; p += 2) {
            long long ra = __builtin_nontemporal_load((const long long*)(pairs + p));
            long long rb = __builtin_nontemporal_load((const long long*)(pairs + p + 1));
            int   ca = (int)ra,            cb = (int)rb;
            float va = __int_as_float((int)(ra >> 32));
            float vb = __int_as_float((int)(rb >> 32));
            float2 wa = *reinterpret_cast<const float2*>(wT + (size_t)ca * OUT_F + 2 * lane);
            float2 wb = *reinterpret_cast<const float2*>(wT + (size_t)cb * OUT_F + 2 * lane);
            acc.x += va * wa.x;
            acc.y += va * wa.y;
            acc.x += vb * wb.x;
            acc.y += vb * wb.y;
        }
        if (p < e) {
            long long ra = __builtin_nontemporal_load((const long long*)(pairs + p));
            int   ca = (int)ra;
            float va = __int_as_float((int)(ra >> 32));
            float2 wa = *reinterpret_cast<const float2*>(wT + (size_t)ca * OUT_F + 2 * lane);
            acc.x += va * wa.x;
            acc.y += va * wa.y;
        }
    }
    if (w > 0) part[w - 1][lane] = acc;
    __syncthreads();
    if (w == 0) {
        float2 b2 = *reinterpret_cast<const float2*>(bias + 2 * lane);
        acc.x += b2.x + part[0][lane].x + part[1][lane].x + part[2][lane].x;
        acc.y += b2.y + part[0][lane].y + part[1][lane].y + part[2][lane].y;
        __builtin_nontemporal_store(acc.x, out + (size_t)row * OUT_F + 2 * lane);
        __builtin_nontemporal_store(acc.y, out + (size_t)row * OUT_F + 2 * lane + 1);
    }
}

// ---------------------------------------------------------------------------
// fallback (ws too small): bias init + atomic scatter — correct but slow
// ---------------------------------------------------------------------------
__global__ void init_out(float4* __restrict__ out4, const float4* __restrict__ bias4) {
    int i = blockIdx.x * blockDim.x + threadIdx.x;
    if (i >= N_ROWS * OUT_F / 4) return;
    out4[i] = bias4[i & 31];
}

__global__ void scatter_noT(const int* __restrict__ rows, const int* __restrict__ cols,
                            const float* __restrict__ vals, const float* __restrict__ w,
                            float* __restrict__ out) {
    int t    = blockIdx.x * blockDim.x + threadIdx.x;
    int nz   = t >> 5;
    int lane = t & 31;
    if (nz >= NNZ) return;
    int   r = rows[nz];
    int   c = cols[nz];
    float v = vals[nz];
    float* o = out + (size_t)r * OUT_F + lane * 4;
    #pragma unroll
    for (int k = 0; k < 4; ++k) {
        float wv = w[(size_t)(lane * 4 + k) * IN_F + c];
        atomicAdd(o + k, v * wv);
    }
}

extern "C" void kernel_launch(void* const* d_in, const int* in_sizes, int n_in,
                              void* d_out, int out_size, void* d_ws, size_t ws_size,
                              hipStream_t stream) {
    const int*   rows   = (const int*)d_in[0];
    const int*   cols   = (const int*)d_in[1];
    const float* vals   = (const float*)d_in[2];
    const float* weight = (const float*)d_in[3];
    const float* bias   = (const float*)d_in[4];
    float* out = (float*)d_out;

    // workspace layout (~26.6 MB). counts+blockSums adjacent for one memset.
    char* ws = (char*)d_ws;
    size_t off = 0;
    float* wT       = (float*)(ws + off); off += (size_t)IN_F * OUT_F * sizeof(float); // 4 MB
    int*   counts   = (int*)(ws + off);   off += (size_t)NPAD2 * 4;                    // 3.2 MB (-> cursors)
    int*   blockSums= (int*)(ws + off);   off += (size_t)SCAN_B * 4;
    int*   offsets  = (int*)(ws + off);   off += (size_t)NPAD2 * 4;                    // 3.2 MB
    off = (off + 7) & ~(size_t)7;
    int2*  pairs    = (int2*)(ws + off);  off += (size_t)NNZ * 8;                      // 16 MB

    if (ws_size >= off) {
        {
            dim3 bdim(32, 8), g(IN_F / 32, OUT_F / 32);
            transpose_w<<<g, bdim, 0, stream>>>(weight, wT);
        }
        hipMemsetAsync(counts, 0, ((size_t)NPAD2 + SCAN_B) * 4, stream);
        {
            int nb = (NNZ + 255) / 256;
            hist8<<<nb, 256, 0, stream>>>(rows, counts);
            scan_blocks<<<NBLK2, SCAN_B, 0, stream>>>(counts, blockSums);
            scan_sums<<<1, SCAN_B, 0, stream>>>(blockSums);
            finalize_offsets<<<NBLK2, SCAN_B, 0, stream>>>(counts, blockSums, offsets);
            scatter8<<<nb, 256, 0, stream>>>(rows, cols, vals, counts, pairs);
        }
        reduce_rows<<<N_ROWS, 256, 0, stream>>>(pairs, wT, offsets, bias, out);
    } else {
        int n4 = N_ROWS * OUT_F / 4;
        init_out<<<(n4 + 255) / 256, 256, 0, stream>>>((float4*)out, (const float4*)bias);
        long long total = (long long)NNZ * 32;
        scatter_noT<<<(int)((total + 255) / 256), 256, 0, stream>>>(rows, cols, vals, weight, out);
    }
}

// Round 7
// 416.786 us; speedup vs baseline: 1.1670x; 1.1670x over previous
//
#include <hip/hip_runtime.h>

#define N_ROWS 100000
#define IN_F   8192
#define OUT_F  128
#define NNZ    2000000

#define NREG   8                                    // regions = XCDs (blockIdx & 7)
#define FLATN  (NREG * N_ROWS)                      // 800000 (region-major counters)
#define SCAN_B 1024
#define NBLK2  ((FLATN + SCAN_B - 1) / SCAN_B)      // 782
#define NPAD2  (NBLK2 * SCAN_B)                     // 800768

__device__ __forceinline__ unsigned short f32_to_bf16_rne(float f) {
    unsigned u = __float_as_uint(f);
    u += 0x7fffu + ((u >> 16) & 1u);                // round to nearest even
    return (unsigned short)(u >> 16);
}

// ---------------------------------------------------------------------------
// transpose weight [OUT_F, IN_F] -> wTb bf16 [IN_F, OUT_F] (2 MB: half an
// XCD-L2, stays resident alongside the pair/offset streams)
// ---------------------------------------------------------------------------
__global__ void transpose_w_bf16(const float* __restrict__ w,
                                 unsigned short* __restrict__ wTb) {
    __shared__ float tile[32][33];
    int x = blockIdx.x * 32 + threadIdx.x;          // c (IN_F dim)
    int y = blockIdx.y * 32 + threadIdx.y;          // out-col (OUT_F dim)
    #pragma unroll
    for (int i = 0; i < 32; i += 8)
        tile[threadIdx.y + i][threadIdx.x] = w[(size_t)(y + i) * IN_F + x];
    __syncthreads();
    int tx = blockIdx.y * 32 + threadIdx.x;         // out-col
    int ty = blockIdx.x * 32 + threadIdx.y;         // c
    #pragma unroll
    for (int i = 0; i < 32; i += 8)
        wTb[(size_t)(ty + i) * OUT_F + tx] = f32_to_bf16_rne(tile[threadIdx.x][threadIdx.y + i]);
}

// ---------------------------------------------------------------------------
// histogram into region-major counters: region j = blockIdx & 7 (== XCD under
// default round-robin dispatch) -> counter lines are XCD-local.
// ---------------------------------------------------------------------------
__global__ void hist8(const int* __restrict__ rows, int* __restrict__ counts) {
    int i = blockIdx.x * blockDim.x + threadIdx.x;
    if (i >= NNZ) return;
    int j = blockIdx.x & 7;
    atomicAdd(&counts[j * N_ROWS + rows[i]], 1);
}

// ---------------------------------------------------------------------------
// per-block exclusive scan, IN PLACE on counts; emits block totals
// ---------------------------------------------------------------------------
__global__ void scan_blocks(int* __restrict__ counts, int* __restrict__ blockSums) {
    __shared__ int sh[SCAN_B];
    int tid = threadIdx.x;
    int gid = blockIdx.x * SCAN_B + tid;
    int v = counts[gid];
    sh[tid] = v;
    __syncthreads();
    for (int off = 1; off < SCAN_B; off <<= 1) {
        int t = (tid >= off) ? sh[tid - off] : 0;
        __syncthreads();
        sh[tid] += t;
        __syncthreads();
    }
    counts[gid] = sh[tid] - v;                     // exclusive within block
    if (tid == SCAN_B - 1) blockSums[blockIdx.x] = sh[tid];
}

// ---------------------------------------------------------------------------
// single-block exclusive scan of blockSums (NBLK2 <= SCAN_B, padding zeroed)
// ---------------------------------------------------------------------------
__global__ void scan_sums(int* __restrict__ blockSums) {
    __shared__ int sh[SCAN_B];
    int tid = threadIdx.x;
    int v = blockSums[tid];
    sh[tid] = v;
    __syncthreads();
    for (int off = 1; off < SCAN_B; off <<= 1) {
        int t = (tid >= off) ? sh[tid - off] : 0;
        __syncthreads();
        sh[tid] += t;
        __syncthreads();
    }
    blockSums[tid] = sh[tid] - v;
}

// ---------------------------------------------------------------------------
// offsets[gid] = scan value (for reduce); counts[gid] := same (cursors)
// ---------------------------------------------------------------------------
__global__ void finalize_offsets(int* __restrict__ counts, const int* __restrict__ blockSums,
                                 int* __restrict__ offsets) {
    int gid = blockIdx.x * SCAN_B + threadIdx.x;
    int off = counts[gid] + blockSums[gid >> 10];
    offsets[gid] = off;
    counts[gid] = off;                             // reuse as cursors
}

// ---------------------------------------------------------------------------
// scatter (col,val) into row-sorted order within this block's region.
// Region pairs-span + cursor lines touched by ONE XCD only (proven r5).
// ---------------------------------------------------------------------------
__global__ void scatter8(const int* __restrict__ rows, const int* __restrict__ cols,
                         const float* __restrict__ vals, int* __restrict__ cursors,
                         int2* __restrict__ pairs) {
    int i = blockIdx.x * blockDim.x + threadIdx.x;
    if (i >= NNZ) return;
    int j = blockIdx.x & 7;                        // MUST match hist8 (same grid shape)
    int r = rows[i];
    int p = atomicAdd(&cursors[j * N_ROWS + r], 1);
    pairs[p] = make_int2(cols[i], __float_as_int(vals[i]));
}

// ---------------------------------------------------------------------------
// one WAVE per row (r5 structure, proven): walk 8 region-segments, register
// accumulate in f32, bf16 weight gather (1 uint = 2 cols per lane), single
// coalesced store. NT pair loads protect wTb L2 residency.
// ---------------------------------------------------------------------------
__global__ void __launch_bounds__(256) reduce_rows(const int2* __restrict__ pairs,
                                                   const unsigned* __restrict__ wTb_u,
                                                   const int* __restrict__ offsets,
                                                   const float* __restrict__ bias,
                                                   float* __restrict__ out) {
    int wid  = (blockIdx.x * blockDim.x + threadIdx.x) >> 6;   // row
    int lane = threadIdx.x & 63;
    if (wid >= N_ROWS) return;
    float2 acc = *reinterpret_cast<const float2*>(bias + 2 * lane);
    #pragma unroll
    for (int j = 0; j < NREG; ++j) {
        int f = j * N_ROWS + wid;
        int p = offsets[f];
        int e = offsets[f + 1];                    // contiguous region-major scan
        for (; p + 2 <= e; p += 2) {
            long long ra = __builtin_nontemporal_load((const long long*)(pairs + p));
            long long rb = __builtin_nontemporal_load((const long long*)(pairs + p + 1));
            int   ca = (int)ra,            cb = (int)rb;
            float va = __int_as_float((int)(ra >> 32));
            float vb = __int_as_float((int)(rb >> 32));
            unsigned wa = wTb_u[(size_t)ca * (OUT_F / 2) + lane];
            unsigned wb = wTb_u[(size_t)cb * (OUT_F / 2) + lane];
            acc.x += va * __uint_as_float(wa << 16);
            acc.y += va * __uint_as_float(wa & 0xffff0000u);
            acc.x += vb * __uint_as_float(wb << 16);
            acc.y += vb * __uint_as_float(wb & 0xffff0000u);
        }
        if (p < e) {
            long long ra = __builtin_nontemporal_load((const long long*)(pairs + p));
            int   ca = (int)ra;
            float va = __int_as_float((int)(ra >> 32));
            unsigned wa = wTb_u[(size_t)ca * (OUT_F / 2) + lane];
            acc.x += va * __uint_as_float(wa << 16);
            acc.y += va * __uint_as_float(wa & 0xffff0000u);
        }
    }
    __builtin_nontemporal_store(acc.x, out + (size_t)wid * OUT_F + 2 * lane);
    __builtin_nontemporal_store(acc.y, out + (size_t)wid * OUT_F + 2 * lane + 1);
}

// ---------------------------------------------------------------------------
// fallback (ws too small): bias init + atomic scatter — correct but slow
// ---------------------------------------------------------------------------
__global__ void init_out(float4* __restrict__ out4, const float4* __restrict__ bias4) {
    int i = blockIdx.x * blockDim.x + threadIdx.x;
    if (i >= N_ROWS * OUT_F / 4) return;
    out4[i] = bias4[i & 31];
}

__global__ void scatter_noT(const int* __restrict__ rows, const int* __restrict__ cols,
                            const float* __restrict__ vals, const float* __restrict__ w,
                            float* __restrict__ out) {
    int t    = blockIdx.x * blockDim.x + threadIdx.x;
    int nz   = t >> 5;
    int lane = t & 31;
    if (nz >= NNZ) return;
    int   r = rows[nz];
    int   c = cols[nz];
    float v = vals[nz];
    float* o = out + (size_t)r * OUT_F + lane * 4;
    #pragma unroll
    for (int k = 0; k < 4; ++k) {
        float wv = w[(size_t)(lane * 4 + k) * IN_F + c];
        atomicAdd(o + k, v * wv);
    }
}

extern "C" void kernel_launch(void* const* d_in, const int* in_sizes, int n_in,
                              void* d_out, int out_size, void* d_ws, size_t ws_size,
                              hipStream_t stream) {
    const int*   rows   = (const int*)d_in[0];
    const int*   cols   = (const int*)d_in[1];
    const float* vals   = (const float*)d_in[2];
    const float* weight = (const float*)d_in[3];
    const float* bias   = (const float*)d_in[4];
    float* out = (float*)d_out;

    // workspace layout (~24.6 MB). counts+blockSums adjacent for one memset.
    char* ws = (char*)d_ws;
    size_t off = 0;
    unsigned short* wTb = (unsigned short*)(ws + off);
    off += (size_t)IN_F * OUT_F * sizeof(unsigned short);                              // 2 MB
    int*   counts   = (int*)(ws + off);   off += (size_t)NPAD2 * 4;                    // 3.2 MB (-> cursors)
    int*   blockSums= (int*)(ws + off);   off += (size_t)SCAN_B * 4;
    int*   offsets  = (int*)(ws + off);   off += (size_t)NPAD2 * 4;                    // 3.2 MB
    off = (off + 7) & ~(size_t)7;
    int2*  pairs    = (int2*)(ws + off);  off += (size_t)NNZ * 8;                      // 16 MB

    if (ws_size >= off) {
        {
            dim3 bdim(32, 8), g(IN_F / 32, OUT_F / 32);
            transpose_w_bf16<<<g, bdim, 0, stream>>>(weight, wTb);
        }
        hipMemsetAsync(counts, 0, ((size_t)NPAD2 + SCAN_B) * 4, stream);
        {
            int nb = (NNZ + 255) / 256;
            hist8<<<nb, 256, 0, stream>>>(rows, counts);
            scan_blocks<<<NBLK2, SCAN_B, 0, stream>>>(counts, blockSums);
            scan_sums<<<1, SCAN_B, 0, stream>>>(blockSums);
            finalize_offsets<<<NBLK2, SCAN_B, 0, stream>>>(counts, blockSums, offsets);
            scatter8<<<nb, 256, 0, stream>>>(rows, cols, vals, counts, pairs);
        }
        {
            int blocks = (N_ROWS + 3) / 4;         // 4 waves (rows) per 256-thread block
            reduce_rows<<<blocks, 256, 0, stream>>>(pairs, (const unsigned*)wTb,
                                                    offsets, bias, out);
        }
    } else {
        int n4 = N_ROWS * OUT_F / 4;
        init_out<<<(n4 + 255) / 256, 256, 0, stream>>>((float4*)out, (const float4*)bias);
        long long total = (long long)NNZ * 32;
        scatter_noT<<<(int)((total + 255) / 256), 256, 0, stream>>>(rows, cols, vals, weight, out);
    }
}

// Round 8
// 326.573 us; speedup vs baseline: 1.4894x; 1.2762x over previous
//
#include <hip/hip_runtime.h>

#define N_ROWS 100000
#define IN_F   8192
#define OUT_F  128
#define NNZ    2000000

#define NREG   8                                    // regions = XCDs (blockIdx & 7)
#define FLATN  (NREG * N_ROWS)                      // 800000 (region-major counters)
#define SCAN_B 1024
#define NBLK2  ((FLATN + SCAN_B - 1) / SCAN_B)      // 782
#define NPAD2  (NBLK2 * SCAN_B)                     // 800768

__device__ __forceinline__ unsigned short f32_to_bf16_rne(float f) {
    unsigned u = __float_as_uint(f);
    u += 0x7fffu + ((u >> 16) & 1u);                // round to nearest even
    return (unsigned short)(u >> 16);
}

// ---------------------------------------------------------------------------
// transpose weight [OUT_F, IN_F] -> wTb bf16 [IN_F, OUT_F] (2 MB, L2-resident)
// ---------------------------------------------------------------------------
__global__ void transpose_w_bf16(const float* __restrict__ w,
                                 unsigned short* __restrict__ wTb) {
    __shared__ float tile[32][33];
    int x = blockIdx.x * 32 + threadIdx.x;          // c (IN_F dim)
    int y = blockIdx.y * 32 + threadIdx.y;          // out-col (OUT_F dim)
    #pragma unroll
    for (int i = 0; i < 32; i += 8)
        tile[threadIdx.y + i][threadIdx.x] = w[(size_t)(y + i) * IN_F + x];
    __syncthreads();
    int tx = blockIdx.y * 32 + threadIdx.x;         // out-col
    int ty = blockIdx.x * 32 + threadIdx.y;         // c
    #pragma unroll
    for (int i = 0; i < 32; i += 8)
        wTb[(size_t)(ty + i) * OUT_F + tx] = f32_to_bf16_rne(tile[threadIdx.x][threadIdx.y + i]);
}

// ---------------------------------------------------------------------------
// histogram into region-major counters (region j = blockIdx & 7 == XCD)
// ---------------------------------------------------------------------------
__global__ void hist8(const int* __restrict__ rows, int* __restrict__ counts) {
    int i = blockIdx.x * blockDim.x + threadIdx.x;
    if (i >= NNZ) return;
    int j = blockIdx.x & 7;
    atomicAdd(&counts[j * N_ROWS + rows[i]], 1);
}

// ---------------------------------------------------------------------------
// per-block exclusive scan, IN PLACE on counts; emits block totals
// ---------------------------------------------------------------------------
__global__ void scan_blocks(int* __restrict__ counts, int* __restrict__ blockSums) {
    __shared__ int sh[SCAN_B];
    int tid = threadIdx.x;
    int gid = blockIdx.x * SCAN_B + tid;
    int v = counts[gid];
    sh[tid] = v;
    __syncthreads();
    for (int off = 1; off < SCAN_B; off <<= 1) {
        int t = (tid >= off) ? sh[tid - off] : 0;
        __syncthreads();
        sh[tid] += t;
        __syncthreads();
    }
    counts[gid] = sh[tid] - v;
    if (tid == SCAN_B - 1) blockSums[blockIdx.x] = sh[tid];
}

__global__ void scan_sums(int* __restrict__ blockSums) {
    __shared__ int sh[SCAN_B];
    int tid = threadIdx.x;
    int v = blockSums[tid];
    sh[tid] = v;
    __syncthreads();
    for (int off = 1; off < SCAN_B; off <<= 1) {
        int t = (tid >= off) ? sh[tid - off] : 0;
        __syncthreads();
        sh[tid] += t;
        __syncthreads();
    }
    blockSums[tid] = sh[tid] - v;
}

__global__ void finalize_offsets(int* __restrict__ counts, const int* __restrict__ blockSums,
                                 int* __restrict__ offsets) {
    int gid = blockIdx.x * SCAN_B + threadIdx.x;
    int off = counts[gid] + blockSums[gid >> 10];
    offsets[gid] = off;
    counts[gid] = off;                             // reuse as cursors
}

// ---------------------------------------------------------------------------
// scatter (col,val) row-sorted within this block's region (XCD-local, r5)
// ---------------------------------------------------------------------------
__global__ void scatter8(const int* __restrict__ rows, const int* __restrict__ cols,
                         const float* __restrict__ vals, int* __restrict__ cursors,
                         int2* __restrict__ pairs) {
    int i = blockIdx.x * blockDim.x + threadIdx.x;
    if (i >= NNZ) return;
    int j = blockIdx.x & 7;                        // MUST match hist8 (same grid shape)
    int r = rows[i];
    int p = atomicAdd(&cursors[j * N_ROWS + r], 1);
    pairs[p] = make_int2(cols[i], __float_as_int(vals[i]));
}

// ---------------------------------------------------------------------------
// one WAVE per row, latency-collapsed:
//   1 parallel load of 8 segment boundaries (lanes 0..15)
//   shfl-scan -> per-lane record position -> 1 parallel load of ALL records
//   k-loop: register broadcast (shfl) + pipelined independent gathers + FMA
// ---------------------------------------------------------------------------
__global__ void __launch_bounds__(256) reduce_rows(const int2* __restrict__ pairs,
                                                   const unsigned* __restrict__ wTb_u,
                                                   const int* __restrict__ offsets,
                                                   const float* __restrict__ bias,
                                                   float* __restrict__ out) {
    int wid  = (blockIdx.x * blockDim.x + threadIdx.x) >> 6;   // row
    int lane = threadIdx.x & 63;
    if (wid >= N_ROWS) return;

    // lane j<8 gets start_j; lane j+8 gets end_j (= offsets[j*N + wid + 1])
    int idx = (lane < 16) ? ((lane & 7) * N_ROWS + wid + (lane >> 3)) : wid;
    int ov  = offsets[idx];
    int startj = ov;                                // lanes 0..7 valid
    int endj   = __shfl(ov, (lane & 7) + 8);
    int len    = endj - startj;                     // lanes 0..7 valid

    // inclusive scan of len over lanes 0..7 (lanes >=8 garbage, unused)
    int incl = len;
    #pragma unroll
    for (int d = 1; d < 8; d <<= 1) {
        int u = __shfl_up(incl, d, 64);
        if (lane >= d) incl += u;
    }
    int cum  = incl - len;                          // exclusive prefix, lanes 0..7
    int diff = startj - cum;                        // lanes 0..7
    int n    = __shfl(incl, 7);                     // row nnz

    float2 acc = *reinterpret_cast<const float2*>(bias + 2 * lane);

    for (int base = 0; base < n; base += 64) {
        int i = base + lane;
        // segment id j = #{k in 1..7 : cum_k <= i}
        int j = 0;
        #pragma unroll
        for (int k = 1; k < 8; ++k)
            j += (i >= __shfl(cum, k)) ? 1 : 0;
        int pos = i + __shfl(diff, j);              // ds_bpermute, per-lane j
        pos = (i < n) ? pos : 0;
        int2 rec = pairs[pos];                      // ONE parallel load: all records
        int cnt = n - base; if (cnt > 64) cnt = 64;
        #pragma unroll 4
        for (int k = 0; k < cnt; ++k) {
            int   c = __shfl(rec.x, k);
            float v = __int_as_float(__shfl(rec.y, k));
            unsigned wv = wTb_u[(size_t)c * (OUT_F / 2) + lane];
            acc.x += v * __uint_as_float(wv << 16);
            acc.y += v * __uint_as_float(wv & 0xffff0000u);
        }
    }
    __builtin_nontemporal_store(acc.x, out + (size_t)wid * OUT_F + 2 * lane);
    __builtin_nontemporal_store(acc.y, out + (size_t)wid * OUT_F + 2 * lane + 1);
}

// ---------------------------------------------------------------------------
// fallback (ws too small): bias init + atomic scatter — correct but slow
// ---------------------------------------------------------------------------
__global__ void init_out(float4* __restrict__ out4, const float4* __restrict__ bias4) {
    int i = blockIdx.x * blockDim.x + threadIdx.x;
    if (i >= N_ROWS * OUT_F / 4) return;
    out4[i] = bias4[i & 31];
}

__global__ void scatter_noT(const int* __restrict__ rows, const int* __restrict__ cols,
                            const float* __restrict__ vals, const float* __restrict__ w,
                            float* __restrict__ out) {
    int t    = blockIdx.x * blockDim.x + threadIdx.x;
    int nz   = t >> 5;
    int lane = t & 31;
    if (nz >= NNZ) return;
    int   r = rows[nz];
    int   c = cols[nz];
    float v = vals[nz];
    float* o = out + (size_t)r * OUT_F + lane * 4;
    #pragma unroll
    for (int k = 0; k < 4; ++k) {
        float wv = w[(size_t)(lane * 4 + k) * IN_F + c];
        atomicAdd(o + k, v * wv);
    }
}

extern "C" void kernel_launch(void* const* d_in, const int* in_sizes, int n_in,
                              void* d_out, int out_size, void* d_ws, size_t ws_size,
                              hipStream_t stream) {
    const int*   rows   = (const int*)d_in[0];
    const int*   cols   = (const int*)d_in[1];
    const float* vals   = (const float*)d_in[2];
    const float* weight = (const float*)d_in[3];
    const float* bias   = (const float*)d_in[4];
    float* out = (float*)d_out;

    // workspace layout (~24.6 MB). counts+blockSums adjacent for one memset.
    char* ws = (char*)d_ws;
    size_t off = 0;
    unsigned short* wTb = (unsigned short*)(ws + off);
    off += (size_t)IN_F * OUT_F * sizeof(unsigned short);                              // 2 MB
    int*   counts   = (int*)(ws + off);   off += (size_t)NPAD2 * 4;                    // 3.2 MB (-> cursors)
    int*   blockSums= (int*)(ws + off);   off += (size_t)SCAN_B * 4;
    int*   offsets  = (int*)(ws + off);   off += (size_t)NPAD2 * 4;                    // 3.2 MB
    off = (off + 7) & ~(size_t)7;
    int2*  pairs    = (int2*)(ws + off);  off += (size_t)NNZ * 8;                      // 16 MB

    if (ws_size >= off) {
        {
            dim3 bdim(32, 8), g(IN_F / 32, OUT_F / 32);
            transpose_w_bf16<<<g, bdim, 0, stream>>>(weight, wTb);
        }
        hipMemsetAsync(counts, 0, ((size_t)NPAD2 + SCAN_B) * 4, stream);
        {
            int nb = (NNZ + 255) / 256;
            hist8<<<nb, 256, 0, stream>>>(rows, counts);
            scan_blocks<<<NBLK2, SCAN_B, 0, stream>>>(counts, blockSums);
            scan_sums<<<1, SCAN_B, 0, stream>>>(blockSums);
            finalize_offsets<<<NBLK2, SCAN_B, 0, stream>>>(counts, blockSums, offsets);
            scatter8<<<nb, 256, 0, stream>>>(rows, cols, vals, counts, pairs);
        }
        {
            int blocks = (N_ROWS + 3) / 4;         // 4 waves (rows) per 256-thread block
            reduce_rows<<<blocks, 256, 0, stream>>>(pairs, (const unsigned*)wTb,
                                                    offsets, bias, out);
        }
    } else {
        int n4 = N_ROWS * OUT_F / 4;
        init_out<<<(n4 + 255) / 256, 256, 0, stream>>>((float4*)out, (const float4*)bias);
        long long total = (long long)NNZ * 32;
        scatter_noT<<<(int)((total + 255) / 256), 256, 0, stream>>>(rows, cols, vals, weight, out);
    }
}

// Round 9
// 147.539 us; speedup vs baseline: 3.2968x; 2.2135x over previous
//
#include <hip/hip_runtime.h>

#define N_ROWS 100000
#define IN_F   8192
#define OUT_F  128
#define NNZ    2000000

#define TILE    4096
#define NTILES  ((NNZ + TILE - 1) / TILE)            // 489
#define NBUCK   ((N_ROWS + 127) / 128)               // 782 buckets of 128 rows
#define FLAT3   (NBUCK * NTILES)                     // 382398
#define SCAN_B  1024
#define NBLK3   ((FLAT3 + SCAN_B - 1) / SCAN_B)      // 374
#define NPAD3   (NBLK3 * SCAN_B)                     // 382976
#define CAPC    3072                                 // bucket mean 2560, +10 sigma

__device__ __forceinline__ unsigned short f32_to_bf16_rne(float f) {
    unsigned u = __float_as_uint(f);
    u += 0x7fffu + ((u >> 16) & 1u);
    return (unsigned short)(u >> 16);
}

// ---------------------------------------------------------------------------
// transpose weight [OUT_F, IN_F] -> wTb bf16 [IN_F, OUT_F] (2 MB, L2-resident)
// ---------------------------------------------------------------------------
__global__ void transpose_w_bf16(const float* __restrict__ w,
                                 unsigned short* __restrict__ wTb) {
    __shared__ float tile[32][33];
    int x = blockIdx.x * 32 + threadIdx.x;
    int y = blockIdx.y * 32 + threadIdx.y;
    #pragma unroll
    for (int i = 0; i < 32; i += 8)
        tile[threadIdx.y + i][threadIdx.x] = w[(size_t)(y + i) * IN_F + x];
    __syncthreads();
    int tx = blockIdx.y * 32 + threadIdx.x;
    int ty = blockIdx.x * 32 + threadIdx.y;
    #pragma unroll
    for (int i = 0; i < 32; i += 8)
        wTb[(size_t)(ty + i) * OUT_F + tx] = f32_to_bf16_rne(tile[threadIdx.x][threadIdx.y + i]);
}

// ---------------------------------------------------------------------------
// A: per-tile bucket histogram (LDS), write tileCnt[b][tile] (bucket-major)
// ---------------------------------------------------------------------------
__global__ void __launch_bounds__(256) tile_hist(const int* __restrict__ rows,
                                                 int* __restrict__ tileCnt) {
    __shared__ int cnt[NBUCK];
    int tile = blockIdx.x, t = threadIdx.x;
    for (int i = t; i < NBUCK; i += 256) cnt[i] = 0;
    __syncthreads();
    int base = tile * TILE;
    int n = NNZ - base; if (n > TILE) n = TILE;
    for (int i = t; i < n; i += 256) atomicAdd(&cnt[rows[base + i] >> 7], 1);
    __syncthreads();
    for (int i = t; i < NBUCK; i += 256) tileCnt[(size_t)i * NTILES + tile] = cnt[i];
}

// ---------------------------------------------------------------------------
// two-level exclusive scan over tileCnt (NPAD3 entries, padding pre-zeroed)
// ---------------------------------------------------------------------------
__global__ void scan_blocks(int* __restrict__ counts, int* __restrict__ blockSums) {
    __shared__ int sh[SCAN_B];
    int tid = threadIdx.x;
    int gid = blockIdx.x * SCAN_B + tid;
    int v = counts[gid];
    sh[tid] = v;
    __syncthreads();
    for (int off = 1; off < SCAN_B; off <<= 1) {
        int t = (tid >= off) ? sh[tid - off] : 0;
        __syncthreads();
        sh[tid] += t;
        __syncthreads();
    }
    counts[gid] = sh[tid] - v;
    if (tid == SCAN_B - 1) blockSums[blockIdx.x] = sh[tid];
}

__global__ void scan_sums(int* __restrict__ blockSums) {
    __shared__ int sh[SCAN_B];
    int tid = threadIdx.x;
    int v = blockSums[tid];
    sh[tid] = v;
    __syncthreads();
    for (int off = 1; off < SCAN_B; off <<= 1) {
        int t = (tid >= off) ? sh[tid - off] : 0;
        __syncthreads();
        sh[tid] += t;
        __syncthreads();
    }
    blockSums[tid] = sh[tid] - v;
}

__global__ void finalize_inplace(int* __restrict__ counts, const int* __restrict__ blockSums) {
    int gid = blockIdx.x * SCAN_B + threadIdx.x;
    counts[gid] += blockSums[gid >> 10];
}

// ---------------------------------------------------------------------------
// B: partition tile into bucket-blocked global layout. LDS counting-sort by
// bucket, then COALESCED runs to exact scanned positions. No global atomics,
// no scattered sub-line stores. record = ((r&127)<<13 | c, val)
// ---------------------------------------------------------------------------
__global__ void __launch_bounds__(256) partition_tiles(const int* __restrict__ rows,
                                                       const int* __restrict__ cols,
                                                       const float* __restrict__ vals,
                                                       const int* __restrict__ scanned,
                                                       int2* __restrict__ pairs) {
    __shared__ int2 stage[TILE];                     // 32 KB
    __shared__ unsigned short sb[TILE];              // 8 KB
    __shared__ int lcnt[NBUCK];                      // 3.1 KB
    __shared__ int loff[1024];                       // 4 KB
    __shared__ int c2[NBUCK];                        // 3.1 KB
    __shared__ int gst[NBUCK];                       // 3.1 KB
    int tile = blockIdx.x, t = threadIdx.x;
    for (int i = t; i < NBUCK; i += 256) {
        lcnt[i] = 0; c2[i] = 0;
        gst[i] = scanned[(size_t)i * NTILES + tile];
    }
    __syncthreads();
    int base = tile * TILE;
    int n = NNZ - base; if (n > TILE) n = TILE;
    // pass 1: count
    for (int i = t; i < n; i += 256) atomicAdd(&lcnt[rows[base + i] >> 7], 1);
    __syncthreads();
    // inclusive scan over 1024 (4 slots/thread Hillis-Steele)
    for (int i = t; i < 1024; i += 256) loff[i] = (i < NBUCK) ? lcnt[i] : 0;
    __syncthreads();
    for (int off = 1; off < 1024; off <<= 1) {
        int v0 = loff[t],       m0 = (t       >= off) ? loff[t       - off] : 0;
        int v1 = loff[t + 256], m1 = (t + 256 >= off) ? loff[t + 256 - off] : 0;
        int v2 = loff[t + 512], m2 = (t + 512 >= off) ? loff[t + 512 - off] : 0;
        int v3 = loff[t + 768], m3 = (t + 768 >= off) ? loff[t + 768 - off] : 0;
        __syncthreads();
        loff[t] = v0 + m0; loff[t + 256] = v1 + m1;
        loff[t + 512] = v2 + m2; loff[t + 768] = v3 + m3;
        __syncthreads();
    }
    // convert to exclusive
    for (int i = t; i < NBUCK; i += 256) loff[i] -= lcnt[i];
    __syncthreads();
    // pass 2: place records into LDS bucket-sorted order
    for (int i = t; i < n; i += 256) {
        int r = rows[base + i];
        int bk = r >> 7;
        int rank = atomicAdd(&c2[bk], 1);
        int s = loff[bk] + rank;
        stage[s] = make_int2(((r & 127) << 13) | cols[base + i],
                             __float_as_int(vals[base + i]));
        sb[s] = (unsigned short)bk;
    }
    __syncthreads();
    // pass 3: coalesced write to exact global positions
    for (int s = t; s < n; s += 256) {
        int bk = sb[s];
        pairs[gst[bk] + (s - loff[bk])] = stage[s];
    }
}

// ---------------------------------------------------------------------------
// C: one block per bucket. LDS counting-sort by row (double-buffered),
// in-place coalesced writeback + per-row offsets emitted directly.
// ---------------------------------------------------------------------------
__global__ void __launch_bounds__(256) bucket_sort_off(int2* __restrict__ pairs,
                                                       const int* __restrict__ scanned,
                                                       int* __restrict__ offsets) {
    __shared__ int2 stA[CAPC];                       // 24 KB
    __shared__ int2 stB[CAPC];                       // 24 KB
    __shared__ int rcnt[128], c2[128], ro[128], roEx[128];
    int b = blockIdx.x, t = threadIdx.x;
    int base = scanned[(size_t)b * NTILES];
    int end  = (b + 1 < NBUCK) ? scanned[(size_t)(b + 1) * NTILES] : NNZ;
    int n = end - base; if (n > CAPC) n = CAPC;      // never hit (+10 sigma)
    if (t < 128) { rcnt[t] = 0; c2[t] = 0; }
    __syncthreads();
    for (int i = t; i < n; i += 256) {
        int2 rec = pairs[base + i];
        stA[i] = rec;
        atomicAdd(&rcnt[rec.x >> 13], 1);
    }
    __syncthreads();
    // scan 128 row counts
    if (t < 128) ro[t] = rcnt[t];
    __syncthreads();
    for (int off = 1; off < 128; off <<= 1) {
        int a = 0;
        if (t < 128 && t >= off) a = ro[t - off];
        __syncthreads();
        if (t < 128) ro[t] += a;
        __syncthreads();
    }
    if (t < 128) {
        int excl = ro[t] - rcnt[t];
        roEx[t] = excl;
        int row = (b << 7) + t;
        if (row < N_ROWS) offsets[row] = base + excl;
    }
    if (b == NBUCK - 1 && t == 0) offsets[N_ROWS] = NNZ;
    __syncthreads();
    // place row-sorted into stB
    for (int i = t; i < n; i += 256) {
        int2 rec = stA[i];
        int rl = rec.x >> 13;
        int rank = atomicAdd(&c2[rl], 1);
        stB[roEx[rl] + rank] = rec;
    }
    __syncthreads();
    // coalesced dense writeback (block owns [base, end) exclusively)
    for (int i = t; i < n; i += 256) pairs[base + i] = stB[i];
}

// ---------------------------------------------------------------------------
// one WAVE per row: single segment, 1 parallel record load, shfl-broadcast FMA
// ---------------------------------------------------------------------------
__global__ void __launch_bounds__(256) reduce_rows(const int2* __restrict__ pairs,
                                                   const unsigned* __restrict__ wTb_u,
                                                   const int* __restrict__ offsets,
                                                   const float* __restrict__ bias,
                                                   float* __restrict__ out) {
    int wid  = (blockIdx.x * blockDim.x + threadIdx.x) >> 6;   // row
    int lane = threadIdx.x & 63;
    if (wid >= N_ROWS) return;
    int start = offsets[wid];
    int end   = offsets[wid + 1];
    float2 acc = *reinterpret_cast<const float2*>(bias + 2 * lane);
    for (int p0 = start; p0 < end; p0 += 64) {
        int i = p0 + lane;
        int2 rec = pairs[i < end ? i : start];       // one parallel load
        int cnt = end - p0; if (cnt > 64) cnt = 64;
        #pragma unroll 4
        for (int k = 0; k < cnt; ++k) {
            int   c = __shfl(rec.x, k) & 8191;
            float v = __int_as_float(__shfl(rec.y, k));
            unsigned wv = wTb_u[(size_t)c * (OUT_F / 2) + lane];
            acc.x += v * __uint_as_float(wv << 16);
            acc.y += v * __uint_as_float(wv & 0xffff0000u);
        }
    }
    __builtin_nontemporal_store(acc.x, out + (size_t)wid * OUT_F + 2 * lane);
    __builtin_nontemporal_store(acc.y, out + (size_t)wid * OUT_F + 2 * lane + 1);
}

// ---------------------------------------------------------------------------
// fallback (ws too small): bias init + atomic scatter — correct but slow
// ---------------------------------------------------------------------------
__global__ void init_out(float4* __restrict__ out4, const float4* __restrict__ bias4) {
    int i = blockIdx.x * blockDim.x + threadIdx.x;
    if (i >= N_ROWS * OUT_F / 4) return;
    out4[i] = bias4[i & 31];
}

__global__ void scatter_noT(const int* __restrict__ rows, const int* __restrict__ cols,
                            const float* __restrict__ vals, const float* __restrict__ w,
                            float* __restrict__ out) {
    int t    = blockIdx.x * blockDim.x + threadIdx.x;
    int nz   = t >> 5;
    int lane = t & 31;
    if (nz >= NNZ) return;
    int   r = rows[nz];
    int   c = cols[nz];
    float v = vals[nz];
    float* o = out + (size_t)r * OUT_F + lane * 4;
    #pragma unroll
    for (int k = 0; k < 4; ++k) {
        float wv = w[(size_t)(lane * 4 + k) * IN_F + c];
        atomicAdd(o + k, v * wv);
    }
}

extern "C" void kernel_launch(void* const* d_in, const int* in_sizes, int n_in,
                              void* d_out, int out_size, void* d_ws, size_t ws_size,
                              hipStream_t stream) {
    const int*   rows   = (const int*)d_in[0];
    const int*   cols   = (const int*)d_in[1];
    const float* vals   = (const float*)d_in[2];
    const float* weight = (const float*)d_in[3];
    const float* bias   = (const float*)d_in[4];
    float* out = (float*)d_out;

    // workspace layout (~20 MB). tileCnt + blockSums adjacent for one memset.
    char* ws = (char*)d_ws;
    size_t off = 0;
    unsigned short* wTb = (unsigned short*)(ws + off);
    off += (size_t)IN_F * OUT_F * sizeof(unsigned short);                 // 2 MB
    int* tileCnt   = (int*)(ws + off); off += (size_t)NPAD3 * 4;          // 1.53 MB
    int* blockSums = (int*)(ws + off); off += (size_t)SCAN_B * 4;         // 4 KB
    int* offsets   = (int*)(ws + off); off += (size_t)(N_ROWS + 2) * 4;   // 400 KB
    off = (off + 7) & ~(size_t)7;
    int2* pairs    = (int2*)(ws + off); off += (size_t)NNZ * 8;           // 16 MB

    if (ws_size >= off) {
        {
            dim3 bdim(32, 8), g(IN_F / 32, OUT_F / 32);
            transpose_w_bf16<<<g, bdim, 0, stream>>>(weight, wTb);
        }
        hipMemsetAsync(tileCnt, 0, ((size_t)NPAD3 + SCAN_B) * 4, stream);
        tile_hist<<<NTILES, 256, 0, stream>>>(rows, tileCnt);
        scan_blocks<<<NBLK3, SCAN_B, 0, stream>>>(tileCnt, blockSums);
        scan_sums<<<1, SCAN_B, 0, stream>>>(blockSums);
        finalize_inplace<<<NBLK3, SCAN_B, 0, stream>>>(tileCnt, blockSums);
        partition_tiles<<<NTILES, 256, 0, stream>>>(rows, cols, vals, tileCnt, pairs);
        bucket_sort_off<<<NBUCK, 256, 0, stream>>>(pairs, tileCnt, offsets);
        reduce_rows<<<(N_ROWS + 3) / 4, 256, 0, stream>>>(pairs, (const unsigned*)wTb,
                                                          offsets, bias, out);
    } else {
        int n4 = N_ROWS * OUT_F / 4;
        init_out<<<(n4 + 255) / 256, 256, 0, stream>>>((float4*)out, (const float4*)bias);
        long long total = (long long)NNZ * 32;
        scatter_noT<<<(int)((total + 255) / 256), 256, 0, stream>>>(rows, cols, vals, weight, out);
    }
}

// Round 11
// 118.142 us; speedup vs baseline: 4.1171x; 1.2488x over previous
//
#include <hip/hip_runtime.h>

#define N_ROWS 100000
#define IN_F   8192
#define OUT_F  128
#define NNZ    2000000

#define TILE    4096
#define NTILES  ((NNZ + TILE - 1) / TILE)            // 489
#define NBUCK   ((N_ROWS + 127) / 128)               // 782 buckets of 128 rows
#define FLAT3   (NBUCK * NTILES)                     // 382398
#define SCAN_B  1024
#define NBLK3   ((FLAT3 + SCAN_B - 1) / SCAN_B)      // 374
#define NPAD3   (NBLK3 * SCAN_B)                     // 382976
#define CAPC    3072                                 // bucket mean 2560, +10 sigma

typedef float f32x4 __attribute__((ext_vector_type(4)));

__device__ __forceinline__ unsigned short f32_to_bf16_rne(float f) {
    unsigned u = __float_as_uint(f);
    u += 0x7fffu + ((u >> 16) & 1u);
    return (unsigned short)(u >> 16);
}

// ---------------------------------------------------------------------------
// transpose weight [OUT_F, IN_F] -> wTb bf16 [IN_F, OUT_F] (2 MB, L2-resident)
// ---------------------------------------------------------------------------
__global__ void transpose_w_bf16(const float* __restrict__ w,
                                 unsigned short* __restrict__ wTb) {
    __shared__ float tile[32][33];
    int x = blockIdx.x * 32 + threadIdx.x;
    int y = blockIdx.y * 32 + threadIdx.y;
    #pragma unroll
    for (int i = 0; i < 32; i += 8)
        tile[threadIdx.y + i][threadIdx.x] = w[(size_t)(y + i) * IN_F + x];
    __syncthreads();
    int tx = blockIdx.y * 32 + threadIdx.x;
    int ty = blockIdx.x * 32 + threadIdx.y;
    #pragma unroll
    for (int i = 0; i < 32; i += 8)
        wTb[(size_t)(ty + i) * OUT_F + tx] = f32_to_bf16_rne(tile[threadIdx.x][threadIdx.y + i]);
}

// ---------------------------------------------------------------------------
// A: per-tile bucket histogram (LDS), write tileCnt[b][tile] (bucket-major).
// Writes ALL entries for its tile column -> no global pre-zero needed.
// ---------------------------------------------------------------------------
__global__ void __launch_bounds__(256) tile_hist(const int* __restrict__ rows,
                                                 int* __restrict__ tileCnt) {
    __shared__ int cnt[NBUCK];
    int tile = blockIdx.x, t = threadIdx.x;
    for (int i = t; i < NBUCK; i += 256) cnt[i] = 0;
    __syncthreads();
    int base = tile * TILE;
    int n = NNZ - base; if (n > TILE) n = TILE;
    for (int i = t; i < n; i += 256) atomicAdd(&cnt[rows[base + i] >> 7], 1);
    __syncthreads();
    for (int i = t; i < NBUCK; i += 256) tileCnt[(size_t)i * NTILES + tile] = cnt[i];
}

// ---------------------------------------------------------------------------
// two-level exclusive scan over tileCnt; out-of-range reads guarded (no memset)
// ---------------------------------------------------------------------------
__global__ void scan_blocks(int* __restrict__ counts, int* __restrict__ blockSums) {
    __shared__ int sh[SCAN_B];
    int tid = threadIdx.x;
    int gid = blockIdx.x * SCAN_B + tid;
    int v = (gid < FLAT3) ? counts[gid] : 0;
    sh[tid] = v;
    __syncthreads();
    for (int off = 1; off < SCAN_B; off <<= 1) {
        int t = (tid >= off) ? sh[tid - off] : 0;
        __syncthreads();
        sh[tid] += t;
        __syncthreads();
    }
    counts[gid] = sh[tid] - v;
    if (tid == SCAN_B - 1) blockSums[blockIdx.x] = sh[tid];
}

__global__ void scan_sums(int* __restrict__ blockSums) {
    __shared__ int sh[SCAN_B];
    int tid = threadIdx.x;
    int v = (tid < NBLK3) ? blockSums[tid] : 0;
    sh[tid] = v;
    __syncthreads();
    for (int off = 1; off < SCAN_B; off <<= 1) {
        int t = (tid >= off) ? sh[tid - off] : 0;
        __syncthreads();
        sh[tid] += t;
        __syncthreads();
    }
    blockSums[tid] = sh[tid] - v;
}

// ---------------------------------------------------------------------------
// B: partition tile into bucket-blocked layout (blockSums add folded in).
// record = ((r&127)<<13 | c, val)
// ---------------------------------------------------------------------------
__global__ void __launch_bounds__(256) partition_tiles(const int* __restrict__ rows,
                                                       const int* __restrict__ cols,
                                                       const float* __restrict__ vals,
                                                       const int* __restrict__ scanned,
                                                       const int* __restrict__ bsum,
                                                       int2* __restrict__ pairs) {
    __shared__ int2 stage[TILE];                     // 32 KB
    __shared__ unsigned short sb[TILE];              // 8 KB
    __shared__ int lcnt[NBUCK];
    __shared__ int loff[1024];
    __shared__ int c2[NBUCK];
    __shared__ int gst[NBUCK];
    int tile = blockIdx.x, t = threadIdx.x;
    for (int i = t; i < NBUCK; i += 256) {
        lcnt[i] = 0; c2[i] = 0;
        int idx = i * NTILES + tile;
        gst[i] = scanned[idx] + bsum[idx >> 10];
    }
    __syncthreads();
    int base = tile * TILE;
    int n = NNZ - base; if (n > TILE) n = TILE;
    for (int i = t; i < n; i += 256) atomicAdd(&lcnt[rows[base + i] >> 7], 1);
    __syncthreads();
    for (int i = t; i < 1024; i += 256) loff[i] = (i < NBUCK) ? lcnt[i] : 0;
    __syncthreads();
    for (int off = 1; off < 1024; off <<= 1) {
        int v0 = loff[t],       m0 = (t       >= off) ? loff[t       - off] : 0;
        int v1 = loff[t + 256], m1 = (t + 256 >= off) ? loff[t + 256 - off] : 0;
        int v2 = loff[t + 512], m2 = (t + 512 >= off) ? loff[t + 512 - off] : 0;
        int v3 = loff[t + 768], m3 = (t + 768 >= off) ? loff[t + 768 - off] : 0;
        __syncthreads();
        loff[t] = v0 + m0; loff[t + 256] = v1 + m1;
        loff[t + 512] = v2 + m2; loff[t + 768] = v3 + m3;
        __syncthreads();
    }
    for (int i = t; i < NBUCK; i += 256) loff[i] -= lcnt[i];
    __syncthreads();
    for (int i = t; i < n; i += 256) {
        int r = rows[base + i];
        int bk = r >> 7;
        int rank = atomicAdd(&c2[bk], 1);
        int s = loff[bk] + rank;
        stage[s] = make_int2(((r & 127) << 13) | cols[base + i],
                             __float_as_int(vals[base + i]));
        sb[s] = (unsigned short)bk;
    }
    __syncthreads();
    for (int s = t; s < n; s += 256) {
        int bk = sb[s];
        pairs[gst[bk] + (s - loff[bk])] = stage[s];
    }
}

// ---------------------------------------------------------------------------
// C: one block per bucket, LDS counting sort by row, coalesced dense
// writeback, per-row offsets emitted (blockSums add folded in).
// ---------------------------------------------------------------------------
__global__ void __launch_bounds__(256) bucket_sort_off(int2* __restrict__ pairs,
                                                       const int* __restrict__ scanned,
                                                       const int* __restrict__ bsum,
                                                       int* __restrict__ offsets) {
    __shared__ int2 stA[CAPC];                       // 24 KB
    __shared__ int2 stB[CAPC];                       // 24 KB
    __shared__ int rcnt[128], c2[128], ro[128], roEx[128];
    int b = blockIdx.x, t = threadIdx.x;
    int i0 = b * NTILES;
    int base = scanned[i0] + bsum[i0 >> 10];
    int end;
    if (b + 1 < NBUCK) { int i1 = (b + 1) * NTILES; end = scanned[i1] + bsum[i1 >> 10]; }
    else end = NNZ;
    int n = end - base; if (n > CAPC) n = CAPC;
    if (t < 128) { rcnt[t] = 0; c2[t] = 0; }
    __syncthreads();
    for (int i = t; i < n; i += 256) {
        int2 rec = pairs[base + i];
        stA[i] = rec;
        atomicAdd(&rcnt[rec.x >> 13], 1);
    }
    __syncthreads();
    if (t < 128) ro[t] = rcnt[t];
    __syncthreads();
    for (int off = 1; off < 128; off <<= 1) {
        int a = 0;
        if (t < 128 && t >= off) a = ro[t - off];
        __syncthreads();
        if (t < 128) ro[t] += a;
        __syncthreads();
    }
    if (t < 128) {
        int excl = ro[t] - rcnt[t];
        roEx[t] = excl;
        int row = (b << 7) + t;
        if (row < N_ROWS) offsets[row] = base + excl;
    }
    if (b == NBUCK - 1 && t == 0) offsets[N_ROWS] = NNZ;
    __syncthreads();
    for (int i = t; i < n; i += 256) {
        int2 rec = stA[i];
        int rl = rec.x >> 13;
        int rank = atomicAdd(&c2[rl], 1);
        stB[roEx[rl] + rank] = rec;
    }
    __syncthreads();
    for (int i = t; i < n; i += 256) pairs[base + i] = stB[i];
}

// ---------------------------------------------------------------------------
// one WAVE per row. 2 records per vmem op: half-wave h handles record k+h,
// lane gathers uint2 (4 cols). 4 groups (8 records) in flight. shfl_down(32)
// combine, single f32x4 NT store from lanes<32.
// ---------------------------------------------------------------------------
__global__ void __launch_bounds__(256) reduce_rows(const int2* __restrict__ pairs,
                                                   const uint2* __restrict__ wT2,
                                                   const int* __restrict__ offsets,
                                                   const float* __restrict__ bias,
                                                   float* __restrict__ out) {
    int wid  = (blockIdx.x * blockDim.x + threadIdx.x) >> 6;   // row
    int lane = threadIdx.x & 63;
    if (wid >= N_ROWS) return;
    int start = offsets[wid];
    int end   = offsets[wid + 1];
    int half = lane >> 5;                              // which record of the pair
    int hl   = lane & 31;                              // lane within half: cols 4hl..4hl+3
    f32x4 acc = {0.f, 0.f, 0.f, 0.f};

    for (int p0 = start; p0 < end; p0 += 64) {
        int i = p0 + lane;
        long long rr = __builtin_nontemporal_load(
            (const long long*)pairs + (i < end ? i : start));
        int rx = (int)rr;
        int ry = (int)(rr >> 32);
        int cnt = end - p0; if (cnt > 64) cnt = 64;
        int k = 0;
        for (; k + 8 <= cnt; k += 8) {                 // 4 paired gathers in flight
            uint2 wv[4]; float vv[4];
            #pragma unroll
            for (int q = 0; q < 4; ++q) {
                int idx = k + 2 * q + half;
                int c = __shfl(rx, idx) & 8191;
                vv[q] = __int_as_float(__shfl(ry, idx));
                wv[q] = wT2[(size_t)c * 32 + hl];
            }
            #pragma unroll
            for (int q = 0; q < 4; ++q) {
                acc.x += vv[q] * __uint_as_float(wv[q].x << 16);
                acc.y += vv[q] * __uint_as_float(wv[q].x & 0xffff0000u);
                acc.z += vv[q] * __uint_as_float(wv[q].y << 16);
                acc.w += vv[q] * __uint_as_float(wv[q].y & 0xffff0000u);
            }
        }
        for (; k < cnt; k += 2) {                      // tail, 2 records at a time
            int idx = k + half;
            int sidx = (idx < cnt) ? idx : k;
            int c = __shfl(rx, sidx) & 8191;
            float v = __int_as_float(__shfl(ry, sidx));
            if (idx >= cnt) v = 0.f;
            uint2 wv = wT2[(size_t)c * 32 + hl];
            acc.x += v * __uint_as_float(wv.x << 16);
            acc.y += v * __uint_as_float(wv.x & 0xffff0000u);
            acc.z += v * __uint_as_float(wv.y << 16);
            acc.w += v * __uint_as_float(wv.y & 0xffff0000u);
        }
    }
    acc.x += __shfl_down(acc.x, 32, 64);
    acc.y += __shfl_down(acc.y, 32, 64);
    acc.z += __shfl_down(acc.z, 32, 64);
    acc.w += __shfl_down(acc.w, 32, 64);
    if (half == 0) {
        const f32x4* b4p = (const f32x4*)(bias + 4 * hl);
        f32x4 b4 = *b4p;
        acc += b4;
        __builtin_nontemporal_store(acc, (f32x4*)(out + (size_t)wid * OUT_F) + hl);
    }
}

// ---------------------------------------------------------------------------
// fallback (ws too small): bias init + atomic scatter — correct but slow
// ---------------------------------------------------------------------------
__global__ void init_out(float4* __restrict__ out4, const float4* __restrict__ bias4) {
    int i = blockIdx.x * blockDim.x + threadIdx.x;
    if (i >= N_ROWS * OUT_F / 4) return;
    out4[i] = bias4[i & 31];
}

__global__ void scatter_noT(const int* __restrict__ rows, const int* __restrict__ cols,
                            const float* __restrict__ vals, const float* __restrict__ w,
                            float* __restrict__ out) {
    int t    = blockIdx.x * blockDim.x + threadIdx.x;
    int nz   = t >> 5;
    int lane = t & 31;
    if (nz >= NNZ) return;
    int   r = rows[nz];
    int   c = cols[nz];
    float v = vals[nz];
    float* o = out + (size_t)r * OUT_F + lane * 4;
    #pragma unroll
    for (int k = 0; k < 4; ++k) {
        float wv = w[(size_t)(lane * 4 + k) * IN_F + c];
        atomicAdd(o + k, v * wv);
    }
}

extern "C" void kernel_launch(void* const* d_in, const int* in_sizes, int n_in,
                              void* d_out, int out_size, void* d_ws, size_t ws_size,
                              hipStream_t stream) {
    const int*   rows   = (const int*)d_in[0];
    const int*   cols   = (const int*)d_in[1];
    const float* vals   = (const float*)d_in[2];
    const float* weight = (const float*)d_in[3];
    const float* bias   = (const float*)d_in[4];
    float* out = (float*)d_out;

    // workspace layout (~20 MB)
    char* ws = (char*)d_ws;
    size_t off = 0;
    unsigned short* wTb = (unsigned short*)(ws + off);
    off += (size_t)IN_F * OUT_F * sizeof(unsigned short);                 // 2 MB
    int* tileCnt   = (int*)(ws + off); off += (size_t)NPAD3 * 4;          // 1.53 MB
    int* blockSums = (int*)(ws + off); off += (size_t)SCAN_B * 4;         // 4 KB
    int* offsets   = (int*)(ws + off); off += (size_t)(N_ROWS + 2) * 4;   // 400 KB
    off = (off + 7) & ~(size_t)7;
    int2* pairs    = (int2*)(ws + off); off += (size_t)NNZ * 8;           // 16 MB

    if (ws_size >= off) {
        {
            dim3 bdim(32, 8), g(IN_F / 32, OUT_F / 32);
            transpose_w_bf16<<<g, bdim, 0, stream>>>(weight, wTb);
        }
        tile_hist<<<NTILES, 256, 0, stream>>>(rows, tileCnt);
        scan_blocks<<<NBLK3, SCAN_B, 0, stream>>>(tileCnt, blockSums);
        scan_sums<<<1, SCAN_B, 0, stream>>>(blockSums);
        partition_tiles<<<NTILES, 256, 0, stream>>>(rows, cols, vals, tileCnt,
                                                    blockSums, pairs);
        bucket_sort_off<<<NBUCK, 256, 0, stream>>>(pairs, tileCnt, blockSums, offsets);
        reduce_rows<<<(N_ROWS + 3) / 4, 256, 0, stream>>>(pairs, (const uint2*)wTb,
                                                          offsets, bias, out);
    } else {
        int n4 = N_ROWS * OUT_F / 4;
        init_out<<<(n4 + 255) / 256, 256, 0, stream>>>((float4*)out, (const float4*)bias);
        long long total = (long long)NNZ * 32;
        scatter_noT<<<(int)((total + 255) / 256), 256, 0, stream>>>(rows, cols, vals, weight, out);
    }
}

// Round 12
// 116.257 us; speedup vs baseline: 4.1839x; 1.0162x over previous
//
#include <hip/hip_runtime.h>

#define N_ROWS 100000
#define IN_F   8192
#define OUT_F  128
#define NNZ    2000000

#define TILE    4096
#define NTILES  ((NNZ + TILE - 1) / TILE)            // 489
#define NBUCK   ((N_ROWS + 127) / 128)               // 782 buckets of 128 rows
#define FLAT3   (NBUCK * NTILES)                     // 382398
#define SCAN_B  1024
#define NBLK3   ((FLAT3 + SCAN_B - 1) / SCAN_B)      // 374
#define NPAD3   (NBLK3 * SCAN_B)                     // 382976
#define CAPC    3072                                 // bucket mean 2560, +10 sigma
#define TRB     ((IN_F / 32) * (OUT_F / 32))         // 1024 transpose blocks

typedef float f32x4 __attribute__((ext_vector_type(4)));

__device__ __forceinline__ unsigned short f32_to_bf16_rne(float f) {
    unsigned u = __float_as_uint(f);
    u += 0x7fffu + ((u >> 16) & 1u);
    return (unsigned short)(u >> 16);
}

// ---------------------------------------------------------------------------
// fused: blocks [0,NTILES) = per-tile bucket histogram;
//        blocks [NTILES, NTILES+TRB) = weight transpose f32->bf16
// ---------------------------------------------------------------------------
__global__ void __launch_bounds__(256) fused_pre(const int* __restrict__ rows,
                                                 int* __restrict__ tileCnt,
                                                 const float* __restrict__ w,
                                                 unsigned short* __restrict__ wTb) {
    __shared__ int smem[32 * 33];                    // max(hist 782, transpose 1056)*4B... use union
    int bid = blockIdx.x, t = threadIdx.x;
    if (bid < NTILES) {
        int* cnt = smem;                             // need NBUCK=782 ints <= 1056 OK
        for (int i = t; i < NBUCK; i += 256) cnt[i] = 0;
        __syncthreads();
        int base = bid * TILE;
        int n = NNZ - base; if (n > TILE) n = TILE;
        for (int i = t; i < n; i += 256) atomicAdd(&cnt[rows[base + i] >> 7], 1);
        __syncthreads();
        for (int i = t; i < NBUCK; i += 256) tileCnt[(size_t)i * NTILES + bid] = cnt[i];
    } else {
        float* tile = (float*)smem;                  // [32][33]
        int b1 = bid - NTILES;
        int gx = b1 & (IN_F / 32 - 1);               // 256 x-blocks
        int gy = b1 >> 8;                            // 4 y-blocks
        int tx = t & 31, ty = t >> 5;                // 32x8
        int x = gx * 32 + tx;
        int y = gy * 32 + ty;
        #pragma unroll
        for (int i = 0; i < 32; i += 8)
            tile[(ty + i) * 33 + tx] = w[(size_t)(y + i) * IN_F + x];
        __syncthreads();
        int ox = gy * 32 + tx;
        int oy = gx * 32 + ty;
        #pragma unroll
        for (int i = 0; i < 32; i += 8)
            wTb[(size_t)(oy + i) * OUT_F + ox] = f32_to_bf16_rne(tile[tx * 33 + ty + i]);
    }
}

// ---------------------------------------------------------------------------
// two-level exclusive scan over tileCnt; out-of-range reads guarded
// ---------------------------------------------------------------------------
__global__ void scan_blocks(int* __restrict__ counts, int* __restrict__ blockSums) {
    __shared__ int sh[SCAN_B];
    int tid = threadIdx.x;
    int gid = blockIdx.x * SCAN_B + tid;
    int v = (gid < FLAT3) ? counts[gid] : 0;
    sh[tid] = v;
    __syncthreads();
    for (int off = 1; off < SCAN_B; off <<= 1) {
        int t = (tid >= off) ? sh[tid - off] : 0;
        __syncthreads();
        sh[tid] += t;
        __syncthreads();
    }
    counts[gid] = sh[tid] - v;
    if (tid == SCAN_B - 1) blockSums[blockIdx.x] = sh[tid];
}

__global__ void scan_sums(int* __restrict__ blockSums) {
    __shared__ int sh[SCAN_B];
    int tid = threadIdx.x;
    int v = (tid < NBLK3) ? blockSums[tid] : 0;
    sh[tid] = v;
    __syncthreads();
    for (int off = 1; off < SCAN_B; off <<= 1) {
        int t = (tid >= off) ? sh[tid - off] : 0;
        __syncthreads();
        sh[tid] += t;
        __syncthreads();
    }
    blockSums[tid] = sh[tid] - v;
}

// ---------------------------------------------------------------------------
// B: partition tile into bucket-blocked layout (blockSums add folded in).
// record = ((r&127)<<13 | c, val)
// ---------------------------------------------------------------------------
__global__ void __launch_bounds__(256) partition_tiles(const int* __restrict__ rows,
                                                       const int* __restrict__ cols,
                                                       const float* __restrict__ vals,
                                                       const int* __restrict__ scanned,
                                                       const int* __restrict__ bsum,
                                                       int2* __restrict__ pairs) {
    __shared__ int2 stage[TILE];                     // 32 KB
    __shared__ unsigned short sb[TILE];              // 8 KB
    __shared__ int lcnt[NBUCK];
    __shared__ int loff[1024];
    __shared__ int c2[NBUCK];
    __shared__ int gst[NBUCK];
    int tile = blockIdx.x, t = threadIdx.x;
    for (int i = t; i < NBUCK; i += 256) {
        lcnt[i] = 0; c2[i] = 0;
        int idx = i * NTILES + tile;
        gst[i] = scanned[idx] + bsum[idx >> 10];
    }
    __syncthreads();
    int base = tile * TILE;
    int n = NNZ - base; if (n > TILE) n = TILE;
    for (int i = t; i < n; i += 256) atomicAdd(&lcnt[rows[base + i] >> 7], 1);
    __syncthreads();
    for (int i = t; i < 1024; i += 256) loff[i] = (i < NBUCK) ? lcnt[i] : 0;
    __syncthreads();
    for (int off = 1; off < 1024; off <<= 1) {
        int v0 = loff[t],       m0 = (t       >= off) ? loff[t       - off] : 0;
        int v1 = loff[t + 256], m1 = (t + 256 >= off) ? loff[t + 256 - off] : 0;
        int v2 = loff[t + 512], m2 = (t + 512 >= off) ? loff[t + 512 - off] : 0;
        int v3 = loff[t + 768], m3 = (t + 768 >= off) ? loff[t + 768 - off] : 0;
        __syncthreads();
        loff[t] = v0 + m0; loff[t + 256] = v1 + m1;
        loff[t + 512] = v2 + m2; loff[t + 768] = v3 + m3;
        __syncthreads();
    }
    for (int i = t; i < NBUCK; i += 256) loff[i] -= lcnt[i];
    __syncthreads();
    for (int i = t; i < n; i += 256) {
        int r = rows[base + i];
        int bk = r >> 7;
        int rank = atomicAdd(&c2[bk], 1);
        int s = loff[bk] + rank;
        stage[s] = make_int2(((r & 127) << 13) | cols[base + i],
                             __float_as_int(vals[base + i]));
        sb[s] = (unsigned short)bk;
    }
    __syncthreads();
    for (int s = t; s < n; s += 256) {
        int bk = sb[s];
        pairs[gst[bk] + (s - loff[bk])] = stage[s];
    }
}

// ---------------------------------------------------------------------------
// C: one block per bucket, LDS counting sort by row, coalesced dense
// writeback, per-row offsets emitted (blockSums add folded in).
// ---------------------------------------------------------------------------
__global__ void __launch_bounds__(256) bucket_sort_off(int2* __restrict__ pairs,
                                                       const int* __restrict__ scanned,
                                                       const int* __restrict__ bsum,
                                                       int* __restrict__ offsets) {
    __shared__ int2 stA[CAPC];                       // 24 KB
    __shared__ int2 stB[CAPC];                       // 24 KB
    __shared__ int rcnt[128], c2[128], ro[128], roEx[128];
    int b = blockIdx.x, t = threadIdx.x;
    int i0 = b * NTILES;
    int base = scanned[i0] + bsum[i0 >> 10];
    int end;
    if (b + 1 < NBUCK) { int i1 = (b + 1) * NTILES; end = scanned[i1] + bsum[i1 >> 10]; }
    else end = NNZ;
    int n = end - base; if (n > CAPC) n = CAPC;
    if (t < 128) { rcnt[t] = 0; c2[t] = 0; }
    __syncthreads();
    for (int i = t; i < n; i += 256) {
        int2 rec = pairs[base + i];
        stA[i] = rec;
        atomicAdd(&rcnt[rec.x >> 13], 1);
    }
    __syncthreads();
    if (t < 128) ro[t] = rcnt[t];
    __syncthreads();
    for (int off = 1; off < 128; off <<= 1) {
        int a = 0;
        if (t < 128 && t >= off) a = ro[t - off];
        __syncthreads();
        if (t < 128) ro[t] += a;
        __syncthreads();
    }
    if (t < 128) {
        int excl = ro[t] - rcnt[t];
        roEx[t] = excl;
        int row = (b << 7) + t;
        if (row < N_ROWS) offsets[row] = base + excl;
    }
    if (b == NBUCK - 1 && t == 0) offsets[N_ROWS] = NNZ;
    __syncthreads();
    for (int i = t; i < n; i += 256) {
        int2 rec = stA[i];
        int rl = rec.x >> 13;
        int rank = atomicAdd(&c2[rl], 1);
        stB[roEx[rl] + rank] = rec;
    }
    __syncthreads();
    for (int i = t; i < n; i += 256) pairs[base + i] = stB[i];
}

// ---------------------------------------------------------------------------
// masked group-of-8: half-wave h handles records k+2q+h; zero-masked past cnt
// ---------------------------------------------------------------------------
__device__ __forceinline__ void group8(int rx, int ry, int k, int cnt, int half,
                                       int hl, const uint2* __restrict__ wT2,
                                       f32x4& acc) {
    uint2 wv[4]; float vv[4];
    #pragma unroll
    for (int q = 0; q < 4; ++q) {
        int idx = k + 2 * q + half;
        int c = __shfl(rx, idx) & 8191;
        float v = __int_as_float(__shfl(ry, idx));
        vv[q] = (idx < cnt) ? v : 0.f;
        wv[q] = wT2[(size_t)c * 32 + hl];
    }
    #pragma unroll
    for (int q = 0; q < 4; ++q) {
        acc.x += vv[q] * __uint_as_float(wv[q].x << 16);
        acc.y += vv[q] * __uint_as_float(wv[q].x & 0xffff0000u);
        acc.z += vv[q] * __uint_as_float(wv[q].y << 16);
        acc.w += vv[q] * __uint_as_float(wv[q].y & 0xffff0000u);
    }
}

// ---------------------------------------------------------------------------
// one WAVE per TWO adjacent rows (contiguous in row-sorted pairs): two
// independent gather chains -> 8 gathers in flight per wave. Branchless
// masked groups (no tail path). shfl_down/shfl_up combine; half0 stores
// row0, half1 stores row1 (one f32x4 NT store per lane).
// ---------------------------------------------------------------------------
__global__ void __launch_bounds__(256, 8) reduce_rows(const int2* __restrict__ pairs,
                                                      const uint2* __restrict__ wT2,
                                                      const int* __restrict__ offsets,
                                                      const float* __restrict__ bias,
                                                      float* __restrict__ out) {
    int wid  = (blockIdx.x * blockDim.x + threadIdx.x) >> 6;   // row pair
    int lane = threadIdx.x & 63;
    int row0 = wid * 2;
    if (row0 >= N_ROWS) return;
    bool has1 = (row0 + 1 < N_ROWS);
    int s0 = offsets[row0];
    int s1 = offsets[row0 + 1];
    int e1 = has1 ? offsets[row0 + 2] : s1;
    int half = lane >> 5;
    int hl   = lane & 31;
    f32x4 acc0 = {0.f, 0.f, 0.f, 0.f};
    f32x4 acc1 = {0.f, 0.f, 0.f, 0.f};

    for (int p0 = s0, p1 = s1; p0 < s1 || p1 < e1; p0 += 64, p1 += 64) {
        int cnt0 = s1 - p0; cnt0 = cnt0 < 0 ? 0 : (cnt0 > 64 ? 64 : cnt0);
        int cnt1 = e1 - p1; cnt1 = cnt1 < 0 ? 0 : (cnt1 > 64 ? 64 : cnt1);
        int i0 = p0 + lane; i0 = (i0 < s1) ? i0 : s0; i0 = i0 < NNZ ? i0 : NNZ - 1;
        int i1 = p1 + lane; i1 = (i1 < e1) ? i1 : s1; i1 = i1 < NNZ ? i1 : NNZ - 1;
        long long rr0 = __builtin_nontemporal_load((const long long*)pairs + i0);
        long long rr1 = __builtin_nontemporal_load((const long long*)pairs + i1);
        int rx0 = (int)rr0, ry0 = (int)(rr0 >> 32);
        int rx1 = (int)rr1, ry1 = (int)(rr1 >> 32);
        int cmax = cnt0 > cnt1 ? cnt0 : cnt1;
        for (int k = 0; k < cmax; k += 8) {
            group8(rx0, ry0, k, cnt0, half, hl, wT2, acc0);
            group8(rx1, ry1, k, cnt1, half, hl, wT2, acc1);
        }
    }
    // combine: acc0 -> half0, acc1 -> half1
    acc0.x += __shfl_down(acc0.x, 32, 64);
    acc0.y += __shfl_down(acc0.y, 32, 64);
    acc0.z += __shfl_down(acc0.z, 32, 64);
    acc0.w += __shfl_down(acc0.w, 32, 64);
    acc1.x += __shfl_up(acc1.x, 32, 64);
    acc1.y += __shfl_up(acc1.y, 32, 64);
    acc1.z += __shfl_up(acc1.z, 32, 64);
    acc1.w += __shfl_up(acc1.w, 32, 64);
    const f32x4 b4 = *(const f32x4*)(bias + 4 * hl);
    if (half == 0) {
        acc0 += b4;
        __builtin_nontemporal_store(acc0, (f32x4*)(out + (size_t)row0 * OUT_F) + hl);
    } else if (has1) {
        acc1 += b4;
        __builtin_nontemporal_store(acc1, (f32x4*)(out + (size_t)(row0 + 1) * OUT_F) + hl);
    }
}

// ---------------------------------------------------------------------------
// fallback (ws too small): bias init + atomic scatter — correct but slow
// ---------------------------------------------------------------------------
__global__ void init_out(float4* __restrict__ out4, const float4* __restrict__ bias4) {
    int i = blockIdx.x * blockDim.x + threadIdx.x;
    if (i >= N_ROWS * OUT_F / 4) return;
    out4[i] = bias4[i & 31];
}

__global__ void scatter_noT(const int* __restrict__ rows, const int* __restrict__ cols,
                            const float* __restrict__ vals, const float* __restrict__ w,
                            float* __restrict__ out) {
    int t    = blockIdx.x * blockDim.x + threadIdx.x;
    int nz   = t >> 5;
    int lane = t & 31;
    if (nz >= NNZ) return;
    int   r = rows[nz];
    int   c = cols[nz];
    float v = vals[nz];
    float* o = out + (size_t)r * OUT_F + lane * 4;
    #pragma unroll
    for (int k = 0; k < 4; ++k) {
        float wv = w[(size_t)(lane * 4 + k) * IN_F + c];
        atomicAdd(o + k, v * wv);
    }
}

extern "C" void kernel_launch(void* const* d_in, const int* in_sizes, int n_in,
                              void* d_out, int out_size, void* d_ws, size_t ws_size,
                              hipStream_t stream) {
    const int*   rows   = (const int*)d_in[0];
    const int*   cols   = (const int*)d_in[1];
    const float* vals   = (const float*)d_in[2];
    const float* weight = (const float*)d_in[3];
    const float* bias   = (const float*)d_in[4];
    float* out = (float*)d_out;

    // workspace layout (~20 MB)
    char* ws = (char*)d_ws;
    size_t off = 0;
    unsigned short* wTb = (unsigned short*)(ws + off);
    off += (size_t)IN_F * OUT_F * sizeof(unsigned short);                 // 2 MB
    int* tileCnt   = (int*)(ws + off); off += (size_t)NPAD3 * 4;          // 1.53 MB
    int* blockSums = (int*)(ws + off); off += (size_t)SCAN_B * 4;         // 4 KB
    int* offsets   = (int*)(ws + off); off += (size_t)(N_ROWS + 2) * 4;   // 400 KB
    off = (off + 7) & ~(size_t)7;
    int2* pairs    = (int2*)(ws + off); off += (size_t)NNZ * 8;           // 16 MB

    if (ws_size >= off) {
        fused_pre<<<NTILES + TRB, 256, 0, stream>>>(rows, tileCnt, weight, wTb);
        scan_blocks<<<NBLK3, SCAN_B, 0, stream>>>(tileCnt, blockSums);
        scan_sums<<<1, SCAN_B, 0, stream>>>(blockSums);
        partition_tiles<<<NTILES, 256, 0, stream>>>(rows, cols, vals, tileCnt,
                                                    blockSums, pairs);
        bucket_sort_off<<<NBUCK, 256, 0, stream>>>(pairs, tileCnt, blockSums, offsets);
        {
            int npairs = (N_ROWS + 1) / 2;           // 50000 row-pairs (waves)
            int blocks = (npairs + 3) / 4;           // 4 waves per 256-thread block
            reduce_rows<<<blocks, 256, 0, stream>>>(pairs, (const uint2*)wTb,
                                                    offsets, bias, out);
        }
    } else {
        int n4 = N_ROWS * OUT_F / 4;
        init_out<<<(n4 + 255) / 256, 256, 0, stream>>>((float4*)out, (const float4*)bias);
        long long total = (long long)NNZ * 32;
        scatter_noT<<<(int)((total + 255) / 256), 256, 0, stream>>>(rows, cols, vals, weight, out);
    }
}

// Round 13
// 111.987 us; speedup vs baseline: 4.3434x; 1.0381x over previous
//
#include <hip/hip_runtime.h>

#define N_ROWS 100000
#define IN_F   8192
#define OUT_F  128
#define NNZ    2000000

#define TILE    4096
#define NTILES  ((NNZ + TILE - 1) / TILE)            // 489
#define NBUCK   ((N_ROWS + 127) / 128)               // 782 buckets of 128 rows
#define FLAT3   (NBUCK * NTILES)                     // 382398
#define SCAN_B  1024
#define NBLK3   ((FLAT3 + SCAN_B - 1) / SCAN_B)      // 374
#define NPAD3   (NBLK3 * SCAN_B)                     // 382976
#define CAPC    3072                                 // bucket mean 2560, +10 sigma
#define TRB     ((IN_F / 32) * (OUT_F / 32))         // 1024 transpose blocks

typedef float f32x4 __attribute__((ext_vector_type(4)));

__device__ __forceinline__ unsigned short f32_to_bf16_rne(float f) {
    unsigned u = __float_as_uint(f);
    u += 0x7fffu + ((u >> 16) & 1u);
    return (unsigned short)(u >> 16);
}

// ---------------------------------------------------------------------------
// fused: blocks [0,NTILES) = per-tile bucket histogram;
//        blocks [NTILES, NTILES+TRB) = weight transpose f32->bf16
// ---------------------------------------------------------------------------
__global__ void __launch_bounds__(256) fused_pre(const int* __restrict__ rows,
                                                 int* __restrict__ tileCnt,
                                                 const float* __restrict__ w,
                                                 unsigned short* __restrict__ wTb) {
    __shared__ int smem[32 * 33];
    int bid = blockIdx.x, t = threadIdx.x;
    if (bid < NTILES) {
        int* cnt = smem;
        for (int i = t; i < NBUCK; i += 256) cnt[i] = 0;
        __syncthreads();
        int base = bid * TILE;
        int n = NNZ - base; if (n > TILE) n = TILE;
        for (int i = t; i < n; i += 256) atomicAdd(&cnt[rows[base + i] >> 7], 1);
        __syncthreads();
        for (int i = t; i < NBUCK; i += 256) tileCnt[(size_t)i * NTILES + bid] = cnt[i];
    } else {
        float* tile = (float*)smem;                  // [32][33]
        int b1 = bid - NTILES;
        int gx = b1 & (IN_F / 32 - 1);               // 256 x-blocks
        int gy = b1 >> 8;                            // 4 y-blocks
        int tx = t & 31, ty = t >> 5;                // 32x8
        int x = gx * 32 + tx;
        int y = gy * 32 + ty;
        #pragma unroll
        for (int i = 0; i < 32; i += 8)
            tile[(ty + i) * 33 + tx] = w[(size_t)(y + i) * IN_F + x];
        __syncthreads();
        int ox = gy * 32 + tx;
        int oy = gx * 32 + ty;
        #pragma unroll
        for (int i = 0; i < 32; i += 8)
            wTb[(size_t)(oy + i) * OUT_F + ox] = f32_to_bf16_rne(tile[tx * 33 + ty + i]);
    }
}

// ---------------------------------------------------------------------------
// two-level exclusive scan over tileCnt; out-of-range reads guarded
// ---------------------------------------------------------------------------
__global__ void scan_blocks(int* __restrict__ counts, int* __restrict__ blockSums) {
    __shared__ int sh[SCAN_B];
    int tid = threadIdx.x;
    int gid = blockIdx.x * SCAN_B + tid;
    int v = (gid < FLAT3) ? counts[gid] : 0;
    sh[tid] = v;
    __syncthreads();
    for (int off = 1; off < SCAN_B; off <<= 1) {
        int t = (tid >= off) ? sh[tid - off] : 0;
        __syncthreads();
        sh[tid] += t;
        __syncthreads();
    }
    counts[gid] = sh[tid] - v;
    if (tid == SCAN_B - 1) blockSums[blockIdx.x] = sh[tid];
}

__global__ void scan_sums(int* __restrict__ blockSums) {
    __shared__ int sh[SCAN_B];
    int tid = threadIdx.x;
    int v = (tid < NBLK3) ? blockSums[tid] : 0;
    sh[tid] = v;
    __syncthreads();
    for (int off = 1; off < SCAN_B; off <<= 1) {
        int t = (tid >= off) ? sh[tid - off] : 0;
        __syncthreads();
        sh[tid] += t;
        __syncthreads();
    }
    blockSums[tid] = sh[tid] - v;
}

// ---------------------------------------------------------------------------
// B: partition tile into bucket-blocked layout (blockSums add folded in).
// record = ((r&127)<<13 | c, val)
// ---------------------------------------------------------------------------
__global__ void __launch_bounds__(256) partition_tiles(const int* __restrict__ rows,
                                                       const int* __restrict__ cols,
                                                       const float* __restrict__ vals,
                                                       const int* __restrict__ scanned,
                                                       const int* __restrict__ bsum,
                                                       int2* __restrict__ pairs) {
    __shared__ int2 stage[TILE];                     // 32 KB
    __shared__ unsigned short sb[TILE];              // 8 KB
    __shared__ int lcnt[NBUCK];
    __shared__ int loff[1024];
    __shared__ int c2[NBUCK];
    __shared__ int gst[NBUCK];
    int tile = blockIdx.x, t = threadIdx.x;
    for (int i = t; i < NBUCK; i += 256) {
        lcnt[i] = 0; c2[i] = 0;
        int idx = i * NTILES + tile;
        gst[i] = scanned[idx] + bsum[idx >> 10];
    }
    __syncthreads();
    int base = tile * TILE;
    int n = NNZ - base; if (n > TILE) n = TILE;
    for (int i = t; i < n; i += 256) atomicAdd(&lcnt[rows[base + i] >> 7], 1);
    __syncthreads();
    for (int i = t; i < 1024; i += 256) loff[i] = (i < NBUCK) ? lcnt[i] : 0;
    __syncthreads();
    for (int off = 1; off < 1024; off <<= 1) {
        int v0 = loff[t],       m0 = (t       >= off) ? loff[t       - off] : 0;
        int v1 = loff[t + 256], m1 = (t + 256 >= off) ? loff[t + 256 - off] : 0;
        int v2 = loff[t + 512], m2 = (t + 512 >= off) ? loff[t + 512 - off] : 0;
        int v3 = loff[t + 768], m3 = (t + 768 >= off) ? loff[t + 768 - off] : 0;
        __syncthreads();
        loff[t] = v0 + m0; loff[t + 256] = v1 + m1;
        loff[t + 512] = v2 + m2; loff[t + 768] = v3 + m3;
        __syncthreads();
    }
    for (int i = t; i < NBUCK; i += 256) loff[i] -= lcnt[i];
    __syncthreads();
    for (int i = t; i < n; i += 256) {
        int r = rows[base + i];
        int bk = r >> 7;
        int rank = atomicAdd(&c2[bk], 1);
        int s = loff[bk] + rank;
        stage[s] = make_int2(((r & 127) << 13) | cols[base + i],
                             __float_as_int(vals[base + i]));
        sb[s] = (unsigned short)bk;
    }
    __syncthreads();
    for (int s = t; s < n; s += 256) {
        int bk = sb[s];
        pairs[gst[bk] + (s - loff[bk])] = stage[s];
    }
}

// ---------------------------------------------------------------------------
// C: one block per bucket, LDS counting sort by row, coalesced dense
// writeback, per-row offsets emitted (blockSums add folded in).
// ---------------------------------------------------------------------------
__global__ void __launch_bounds__(256) bucket_sort_off(int2* __restrict__ pairs,
                                                       const int* __restrict__ scanned,
                                                       const int* __restrict__ bsum,
                                                       int* __restrict__ offsets) {
    __shared__ int2 stA[CAPC];                       // 24 KB
    __shared__ int2 stB[CAPC];                       // 24 KB
    __shared__ int rcnt[128], c2[128], ro[128], roEx[128];
    int b = blockIdx.x, t = threadIdx.x;
    int i0 = b * NTILES;
    int base = scanned[i0] + bsum[i0 >> 10];
    int end;
    if (b + 1 < NBUCK) { int i1 = (b + 1) * NTILES; end = scanned[i1] + bsum[i1 >> 10]; }
    else end = NNZ;
    int n = end - base; if (n > CAPC) n = CAPC;
    if (t < 128) { rcnt[t] = 0; c2[t] = 0; }
    __syncthreads();
    for (int i = t; i < n; i += 256) {
        int2 rec = pairs[base + i];
        stA[i] = rec;
        atomicAdd(&rcnt[rec.x >> 13], 1);
    }
    __syncthreads();
    if (t < 128) ro[t] = rcnt[t];
    __syncthreads();
    for (int off = 1; off < 128; off <<= 1) {
        int a = 0;
        if (t < 128 && t >= off) a = ro[t - off];
        __syncthreads();
        if (t < 128) ro[t] += a;
        __syncthreads();
    }
    if (t < 128) {
        int excl = ro[t] - rcnt[t];
        roEx[t] = excl;
        int row = (b << 7) + t;
        if (row < N_ROWS) offsets[row] = base + excl;
    }
    if (b == NBUCK - 1 && t == 0) offsets[N_ROWS] = NNZ;
    __syncthreads();
    for (int i = t; i < n; i += 256) {
        int2 rec = stA[i];
        int rl = rec.x >> 13;
        int rank = atomicAdd(&c2[rl], 1);
        stB[roEx[rl] + rank] = rec;
    }
    __syncthreads();
    for (int i = t; i < n; i += 256) pairs[base + i] = stB[i];
}

// ---------------------------------------------------------------------------
// one WAVE per row, LDS uniform-broadcast:
//   chunk: 64-record parallel NT load -> zero-masked -> ds_write_b64 into a
//   wave-private LDS slot (no barrier).
//   inner: pair p via ONE ds_read_b64 at base+half*8, immediate offset 16p
//   (same-address broadcast, zero VALU, no masks). Half-wave h handles record
//   2p+h, lane gathers uint2 (4 cols). 4 pairs per sub-iter in flight.
// ---------------------------------------------------------------------------
__global__ void __launch_bounds__(256, 8) reduce_rows(const int2* __restrict__ pairs,
                                                      const uint2* __restrict__ wT2,
                                                      const int* __restrict__ offsets,
                                                      const float* __restrict__ bias,
                                                      float* __restrict__ out) {
    __shared__ unsigned long long stg[4][64];        // 2 KB, wave-private slots
    int t    = threadIdx.x;
    int wv   = t >> 6;
    int lane = t & 63;
    int wid  = blockIdx.x * 4 + wv;                  // row
    if (wid >= N_ROWS) return;
    int start = offsets[wid];
    int end   = offsets[wid + 1];
    int half = lane >> 5;
    int hl   = lane & 31;
    unsigned long long* mystg = stg[wv];
    f32x4 acc = {0.f, 0.f, 0.f, 0.f};

    for (int p0 = start; p0 < end; p0 += 64) {
        int i = p0 + lane;
        bool inb = i < end;
        long long rr = __builtin_nontemporal_load(
            (const long long*)pairs + (inb ? i : start));
        if (!inb) rr = 0;                            // c=0, v=0 -> harmless
        mystg[lane] = (unsigned long long)rr;
        int cnt = end - p0; if (cnt > 64) cnt = 64;
        for (int k = 0; k < cnt; k += 8) {           // 4 pairs per sub-iter
            #pragma unroll
            for (int q = 0; q < 4; ++q) {
                unsigned long long r = mystg[k + 2 * q + half];  // broadcast read
                unsigned c = (unsigned)r & 8191u;
                float    v = __uint_as_float((unsigned)(r >> 32));
                uint2 w = wT2[(size_t)c * 32 + hl];
                acc.x += v * __uint_as_float(w.x << 16);
                acc.y += v * __uint_as_float(w.x & 0xffff0000u);
                acc.z += v * __uint_as_float(w.y << 16);
                acc.w += v * __uint_as_float(w.y & 0xffff0000u);
            }
        }
    }
    acc.x += __shfl_down(acc.x, 32, 64);
    acc.y += __shfl_down(acc.y, 32, 64);
    acc.z += __shfl_down(acc.z, 32, 64);
    acc.w += __shfl_down(acc.w, 32, 64);
    if (half == 0) {
        const f32x4 b4 = *(const f32x4*)(bias + 4 * hl);
        acc += b4;
        __builtin_nontemporal_store(acc, (f32x4*)(out + (size_t)wid * OUT_F) + hl);
    }
}

// ---------------------------------------------------------------------------
// fallback (ws too small): bias init + atomic scatter — correct but slow
// ---------------------------------------------------------------------------
__global__ void init_out(float4* __restrict__ out4, const float4* __restrict__ bias4) {
    int i = blockIdx.x * blockDim.x + threadIdx.x;
    if (i >= N_ROWS * OUT_F / 4) return;
    out4[i] = bias4[i & 31];
}

__global__ void scatter_noT(const int* __restrict__ rows, const int* __restrict__ cols,
                            const float* __restrict__ vals, const float* __restrict__ w,
                            float* __restrict__ out) {
    int t    = blockIdx.x * blockDim.x + threadIdx.x;
    int nz   = t >> 5;
    int lane = t & 31;
    if (nz >= NNZ) return;
    int   r = rows[nz];
    int   c = cols[nz];
    float v = vals[nz];
    float* o = out + (size_t)r * OUT_F + lane * 4;
    #pragma unroll
    for (int k = 0; k < 4; ++k) {
        float wv = w[(size_t)(lane * 4 + k) * IN_F + c];
        atomicAdd(o + k, v * wv);
    }
}

extern "C" void kernel_launch(void* const* d_in, const int* in_sizes, int n_in,
                              void* d_out, int out_size, void* d_ws, size_t ws_size,
                              hipStream_t stream) {
    const int*   rows   = (const int*)d_in[0];
    const int*   cols   = (const int*)d_in[1];
    const float* vals   = (const float*)d_in[2];
    const float* weight = (const float*)d_in[3];
    const float* bias   = (const float*)d_in[4];
    float* out = (float*)d_out;

    // workspace layout (~20 MB)
    char* ws = (char*)d_ws;
    size_t off = 0;
    unsigned short* wTb = (unsigned short*)(ws + off);
    off += (size_t)IN_F * OUT_F * sizeof(unsigned short);                 // 2 MB
    int* tileCnt   = (int*)(ws + off); off += (size_t)NPAD3 * 4;          // 1.53 MB
    int* blockSums = (int*)(ws + off); off += (size_t)SCAN_B * 4;         // 4 KB
    int* offsets   = (int*)(ws + off); off += (size_t)(N_ROWS + 2) * 4;   // 400 KB
    off = (off + 7) & ~(size_t)7;
    int2* pairs    = (int2*)(ws + off); off += (size_t)NNZ * 8;           // 16 MB

    if (ws_size >= off) {
        fused_pre<<<NTILES + TRB, 256, 0, stream>>>(rows, tileCnt, weight, wTb);
        scan_blocks<<<NBLK3, SCAN_B, 0, stream>>>(tileCnt, blockSums);
        scan_sums<<<1, SCAN_B, 0, stream>>>(blockSums);
        partition_tiles<<<NTILES, 256, 0, stream>>>(rows, cols, vals, tileCnt,
                                                    blockSums, pairs);
        bucket_sort_off<<<NBUCK, 256, 0, stream>>>(pairs, tileCnt, blockSums, offsets);
        reduce_rows<<<(N_ROWS + 3) / 4, 256, 0, stream>>>(pairs, (const uint2*)wTb,
                                                          offsets, bias, out);
    } else {
        int n4 = N_ROWS * OUT_F / 4;
        init_out<<<(n4 + 255) / 256, 256, 0, stream>>>((float4*)out, (const float4*)bias);
        long long total = (long long)NNZ * 32;
        scatter_noT<<<(int)((total + 255) / 256), 256, 0, stream>>>(rows, cols, vals, weight, out);
    }
}